// Round 8
// baseline (2353.617 us; speedup 1.0000x reference)
//
#include <hip/hip_runtime.h>
#include <hip/hip_bf16.h>

#define DEV __device__ __forceinline__

typedef __bf16 bf16x8 __attribute__((ext_vector_type(8)));
typedef float  f32x4  __attribute__((ext_vector_type(4)));
typedef unsigned short u16;

DEV u16   f2b(float f) { __bf16 h = (__bf16)f; return __builtin_bit_cast(u16, h); }
DEV float b2f(u16 x)   { return __builtin_bit_cast(float, ((unsigned)x) << 16); }

DEV void gl_lds16(const u16* g, u16* l) {
  __builtin_amdgcn_global_load_lds((const __attribute__((address_space(1))) void*)g,
                                   (__attribute__((address_space(3))) void*)l, 16, 0, 0);
}

struct SqCfg {
  const u16 *A0, *A1, *A2, *A3, *B0, *B1, *B2, *B3;
  u16 *o10, *o11, *o12, *o13, *t0, *t1, *t2, *t3, *c0, *c1, *c2, *c3;
};

// ---------------------------------------------------------------------------
// 64x64-tile GEMM, BK=128 double-buffered LDS (R7-proven core).
// MODE 0: phase1  — K=4096, A = x segs (cmul4 map), B = Xcat slots 0..3;
//                   out lC fp32 += bq[3].
// MODE 1: squaring z-batch — K=1024, plain A/B (stride 1024); out o1/o1T/ocat.
// MODE 3: phase3  — q=4-z, K=(q+1)*1024: seg0 = chain (bnd_b, Wcat slot 4-q),
//                   segs 1..q = x segs (Xcat slots); += bq[q-1];
//                   out hall[t], out0[t-1] (h^2*sigmoid fused).
// ---------------------------------------------------------------------------
template<int MODE>
__global__ __launch_bounds__(256) void gX(
    const u16* __restrict__ xb, const u16* __restrict__ chain,
    const u16* __restrict__ Wcat, const u16* __restrict__ Xcat,
    const float* __restrict__ bq, float* __restrict__ lC,
    float* __restrict__ hall, float* __restrict__ out0, SqCfg sq)
{
  int q = 0, nseg;
  if (MODE == 3)      { q = 4 - (int)blockIdx.z; nseg = q + 1; }
  else if (MODE == 0) { nseg = 4; }
  else                { nseg = 1; }
  const int K = nseg << 10;

  const u16 *m1A = nullptr, *m1B = nullptr;
  u16 *m1o1 = nullptr, *m1T = nullptr, *m1c = nullptr;
  if (MODE == 1) {
    switch (blockIdx.z) {
      case 0: m1A = sq.A0; m1B = sq.B0; m1o1 = sq.o10; m1T = sq.t0; m1c = sq.c0; break;
      case 1: m1A = sq.A1; m1B = sq.B1; m1o1 = sq.o11; m1T = sq.t1; m1c = sq.c1; break;
      case 2: m1A = sq.A2; m1B = sq.B2; m1o1 = sq.o12; m1T = sq.t2; m1c = sq.c2; break;
      default: m1A = sq.A3; m1B = sq.B3; m1o1 = sq.o13; m1T = sq.t3; m1c = sq.c3; break;
    }
  }

  int tid = threadIdx.x, lane = tid & 63, w = tid >> 6;
  int wrow = (w >> 1) << 5, wcol = (w & 1) << 5;
  int m0 = blockIdx.y << 6, e0 = blockIdx.x << 6;

  __shared__ u16 As[2][8192], Bs[2][8192];
  f32x4 acc[2][2] = {};

  int rA[4], cA[4];
#pragma unroll
  for (int j = 0; j < 4; ++j) {
    int p = (j * 4 + w) * 1024 + lane * 16;
    int r = p >> 8, o = (p & 255) ^ ((r & 7) << 4);
    rA[j] = r; cA[j] = o >> 1;
  }
  auto stage = [&](int buf, int kt) {
    int seg = kt >> 10, kl = kt & 1023;
    const u16* ap; const u16* bp; int xm, ct = 0, bst;
    if (MODE == 1)      { ap = m1A; bp = m1B; xm = 0; bst = 1024; }
    else if (MODE == 0) { ap = xb; xm = 1; ct = seg; bp = Xcat + (seg << 10); bst = 4096; }
    else {
      bst = 4096;
      if (seg == 0) { ap = chain; xm = 0; bp = Wcat + ((4 - q) << 10); }
      else          { ap = xb; xm = 1; ct = seg - 1; bp = Xcat + ((3 - q + seg) << 10); }
    }
#pragma unroll
    for (int j = 0; j < 4; ++j) {
      int grow = m0 + rA[j];
      long row = xm ? ((long)((grow >> 3) * 4 + ct) * 8 + (grow & 7)) : (long)grow;
      gl_lds16(ap + row * 1024 + kl + cA[j], &As[buf][(j * 4 + w) * 512]);
    }
#pragma unroll
    for (int j = 0; j < 4; ++j)
      gl_lds16(bp + (size_t)(e0 + rA[j]) * bst + kl + cA[j], &Bs[buf][(j * 4 + w) * 512]);
  };

  stage(0, 0);
  asm volatile("s_waitcnt vmcnt(0)" ::: "memory");
  __syncthreads();

  int buf = 0;
  for (int kt = 0; kt < K; kt += 128, buf ^= 1) {
    if (kt + 128 < K) stage(buf ^ 1, kt + 128);
#pragma unroll
    for (int ks = 0; ks < 4; ++ks) {
      int oa = ks * 64 + ((lane >> 4) << 4);
      bf16x8 af[2], bf[2];
#pragma unroll
      for (int s = 0; s < 2; ++s) {
        int ra = wrow + s * 16 + (lane & 15);
        int rb = wcol + s * 16 + (lane & 15);
        af[s] = *(const bf16x8*)((const char*)&As[buf][0] + ra * 256 + (oa ^ ((ra & 7) << 4)));
        bf[s] = *(const bf16x8*)((const char*)&Bs[buf][0] + rb * 256 + (oa ^ ((rb & 7) << 4)));
      }
#pragma unroll
      for (int ms = 0; ms < 2; ++ms)
#pragma unroll
        for (int ns = 0; ns < 2; ++ns)
          acc[ms][ns] = __builtin_amdgcn_mfma_f32_16x16x32_bf16(af[ms], bf[ns], acc[ms][ns], 0, 0, 0);
    }
    asm volatile("s_waitcnt vmcnt(0)" ::: "memory");
    __syncthreads();
  }

  int l4 = ((lane >> 4) << 2), lc = lane & 15;
#pragma unroll
  for (int ms = 0; ms < 2; ++ms)
#pragma unroll
    for (int ns = 0; ns < 2; ++ns)
#pragma unroll
      for (int j = 0; j < 4; ++j) {
        int row = m0 + wrow + ms * 16 + l4 + j;   // C/D: row=(lane>>4)*4+reg
        int col = e0 + wcol + ns * 16 + lc;       // C/D: col=lane&15
        float v = acc[ms][ns][j];
        if (MODE == 0) {
          lC[(size_t)row * 1024 + col] = v + bq[3072 + col];
        } else if (MODE == 1) {
          u16 h = f2b(v);
          if (m1o1) m1o1[(size_t)row * 1024 + col] = h;
          if (m1T)  m1T[(size_t)col * 1024 + row] = h;
          if (m1c)  m1c[(size_t)row * 4096 + col] = h;
        } else {
          v += bq[(q - 1) * 1024 + col];
          int t = (row >> 3) * 4 + q, b = row & 7;
          hall[(size_t)t * 8192 + b * 1024 + col] = v;
          float sg = 1.f / (1.f + __expf(-v));
          out0[(size_t)(t - 1) * 8192 + b * 1024 + col] = v * v * sg;
        }
      }
}

// ---------------------------------------------------------------------------
// z-batched matvec: out = Wc*vin + sum_t (Wt_t ? Wt_t*xt_t : xt_t) ; fp32 state.
// maps: 0 -> row = r; 1 -> row = (r>>3)*128 + (r&7)  (lC/bnd chunk spread)
// ---------------------------------------------------------------------------
struct MvCfg {
  const float* vin; const u16* Wc;
  const u16 *Wt0, *Wt1, *Wt2, *Wt3;
  const float *xt0, *xt1, *xt2, *xt3;
  float* vout; u16* outb;
  int nterm, xmap, omap;
};
struct MvzArgs { MvCfg z0, z1, z2, z3; };

DEV int rmap(int r, int m) { return m ? ((r >> 3) * 128 + (r & 7)) : r; }

DEV void term_acc(const u16* Wt, const float* xt, int xmap, int r0, int d0, int e,
                  float acc[8])
{
  const u16* wr = Wt + (size_t)e * 1024 + d0;
  ushort4 w0 = *(const ushort4*)(wr);
  ushort4 w1 = *(const ushort4*)(wr + 4);
  float wa = b2f(w0.x), wb = b2f(w0.y), wc = b2f(w0.z), wd = b2f(w0.w);
  float we_ = b2f(w1.x), wf = b2f(w1.y), wg = b2f(w1.z), wh = b2f(w1.w);
#pragma unroll
  for (int b = 0; b < 8; ++b) {
    const float* xr = xt + (size_t)rmap(r0 + b, xmap) * 1024 + d0;
    float4 h0v = *(const float4*)xr;
    float4 h1v = *(const float4*)(xr + 4);
    acc[b] += wa*h0v.x + wb*h0v.y + wc*h0v.z + wd*h0v.w
            + we_*h1v.x + wf*h1v.y + wg*h1v.z + wh*h1v.w;
  }
}

__global__ __launch_bounds__(256) void mvz(MvzArgs a)
{
  MvCfg c;
  switch (blockIdx.z) { case 0: c = a.z0; break; case 1: c = a.z1; break;
                        case 2: c = a.z2; break; default: c = a.z3; break; }
  int tid = threadIdx.x, lg = tid & 15, eg = tid >> 4;
  int e = blockIdx.x * 16 + eg;
  int r0 = blockIdx.y * 8;
  float acc[8] = {0,0,0,0,0,0,0,0};
#pragma unroll 1
  for (int i = 0; i < 8; ++i) {
    int d0 = lg * 8 + i * 128;
    term_acc(c.Wc, c.vin, 0, r0, d0, e, acc);
    if (c.nterm > 0 && c.Wt0) term_acc(c.Wt0, c.xt0, c.xmap, r0, d0, e, acc);
    if (c.nterm > 1 && c.Wt1) term_acc(c.Wt1, c.xt1, c.xmap, r0, d0, e, acc);
    if (c.nterm > 2 && c.Wt2) term_acc(c.Wt2, c.xt2, c.xmap, r0, d0, e, acc);
    if (c.nterm > 3 && c.Wt3) term_acc(c.Wt3, c.xt3, c.xmap, r0, d0, e, acc);
  }
#pragma unroll
  for (int m = 1; m < 16; m <<= 1)
#pragma unroll
    for (int b = 0; b < 8; ++b) acc[b] += __shfl_xor(acc[b], m);
  if (lg == 0) {
#pragma unroll
    for (int b = 0; b < 8; ++b) {
      int r = r0 + b;
      float v = acc[b];
      if (c.nterm > 0 && !c.Wt0) v += c.xt0[(size_t)rmap(r, c.xmap) * 1024 + e];
      if (c.nterm > 1 && !c.Wt1) v += c.xt1[(size_t)rmap(r, c.xmap) * 1024 + e];
      if (c.nterm > 2 && !c.Wt2) v += c.xt2[(size_t)rmap(r, c.xmap) * 1024 + e];
      if (c.nterm > 3 && !c.Wt3) v += c.xt3[(size_t)rmap(r, c.xmap) * 1024 + e];
      if (c.vout) c.vout[(size_t)r * 1024 + e] = v;
      if (c.outb) c.outb[(size_t)rmap(r, c.omap) * 1024 + e] = f2b(v);
    }
  }
}

// ---- small helpers ----------------------------------------------------------
__global__ void k_init(const float* __restrict__ u_in, const float* __restrict__ h0,
                       float* __restrict__ u_cur, float* __restrict__ v_acc,
                       float* __restrict__ u_acc, float* __restrict__ hall0,
                       float* __restrict__ bndS, u16* __restrict__ bndb)
{
  int i = blockIdx.x * 256 + threadIdx.x;
  if (i < 1024) { u_cur[i] = u_in[i]; v_acc[i] = 0.f; u_acc[i] = 0.f; }
  if (i < 8192) { float h = h0[i]; hall0[i] = h; bndS[i] = h; bndb[i] = f2b(h); }
}

__global__ void k_v(const float* __restrict__ W, const float* __restrict__ u_cur,
                    float* __restrict__ v_acc)
{
  int d = blockIdx.x * 256 + threadIdx.x;
  int e0 = blockIdx.y * 64;
  float a = 0.f;
  for (int e = e0; e < e0 + 64; ++e) a += W[(size_t)e * 1024 + d] * u_cur[e];
  atomicAdd(&v_acc[d], a);
}

__global__ void k_u(const float* __restrict__ W, const float* __restrict__ v_cur,
                    float* __restrict__ u_acc)
{
  int lg = threadIdx.x & 15, ei = threadIdx.x >> 4;
  int e = blockIdx.y * 16 + ei;
  int d0 = blockIdx.x * 512;
  float a = 0.f;
  for (int i = 0; i < 32; ++i) { int d = d0 + lg + 16 * i; a += W[(size_t)e * 1024 + d] * v_cur[d]; }
#pragma unroll
  for (int m = 1; m < 16; m <<= 1) a += __shfl_xor(a, m);
  if (lg == 0) atomicAdd(&u_acc[e], a);
}

__global__ void k_norm(const float* __restrict__ acc, float* __restrict__ outv,
                       float* __restrict__ z1)
{
  __shared__ float red[16];
  int t = threadIdx.x;
  float x = acc[t];
  float ss = x * x;
#pragma unroll
  for (int m = 1; m < 64; m <<= 1) ss += __shfl_xor(ss, m);
  if ((t & 63) == 0) red[t >> 6] = ss;
  __syncthreads();
  if (t < 64) {
    float s = (t < 16) ? red[t] : 0.f;
#pragma unroll
    for (int m = 1; m < 16; m <<= 1) s += __shfl_xor(s, m);
    if (t == 0) red[0] = s;
  }
  __syncthreads();
  float nrm = sqrtf(red[0]) + 1e-8f;
  outv[t] = x / nrm;
  z1[t] = 0.f;
}

__global__ void k_sigma(const float* __restrict__ acc, float* __restrict__ scale)
{
  __shared__ float red[16];
  int t = threadIdx.x;
  float x = acc[t];
  float ss = x * x;
#pragma unroll
  for (int m = 1; m < 64; m <<= 1) ss += __shfl_xor(ss, m);
  if ((t & 63) == 0) red[t >> 6] = ss;
  __syncthreads();
  if (t < 64) {
    float s = (t < 16) ? red[t] : 0.f;
#pragma unroll
    for (int m = 1; m < 16; m <<= 1) s += __shfl_xor(s, m);
    if (t == 0) {
      float sigma = s / (sqrtf(s) + 1e-8f);
      scale[0] = 0.95f / (sigma + 1e-8f);
    }
  }
}

// Wh*scale -> wh_b, whT, Wcat slot3; Wx -> wxT, Xcat slot3
__global__ void k_prep(const float* __restrict__ Wh, const float* __restrict__ Wx,
                       const float* __restrict__ scale, u16* __restrict__ wh_b,
                       u16* __restrict__ whT, u16* __restrict__ wxT,
                       u16* __restrict__ Wcat, u16* __restrict__ Xcat)
{
  int i = blockIdx.x * 256 + threadIdx.x;
  float s = scale[0];
  int e = i >> 10, d = i & 1023;
  u16 hw = f2b(Wh[i] * s), hx = f2b(Wx[i]);
  wh_b[i] = hw;
  whT[(size_t)d * 1024 + e] = hw;
  Wcat[(size_t)e * 4096 + 3072 + d] = hw;
  wxT[(size_t)d * 1024 + e] = hx;
  Xcat[(size_t)e * 4096 + 3072 + d] = hx;
}

// bq[q-1] = (sum_{j<q} W^j) b, q=1..4  (one WG, sequential matvecs)
__global__ void k_bq(const float* __restrict__ b, const u16* __restrict__ wh,
                     float* __restrict__ bq)
{
  __shared__ float sb[1024];
  int e = threadIdx.x;
  float cur = b[e];
  bq[e] = cur;
  for (int qq = 2; qq <= 4; ++qq) {
    sb[e] = cur;
    __syncthreads();
    float a = 0.f;
    for (int d = 0; d < 1024; ++d) a += b2f(wh[(size_t)e * 1024 + d]) * sb[d];
    cur = a + b[e];
    bq[(qq - 1) * 1024 + e] = cur;
    __syncthreads();
  }
}

__global__ void k_cvt(const float* __restrict__ in, u16* __restrict__ out, int n)
{
  int i = (blockIdx.x * 256 + threadIdx.x) * 4;
  if (i >= n) return;
  float4 v = *(const float4*)(in + i);
  ushort4 o;
  o.x = f2b(v.x); o.y = f2b(v.y); o.z = f2b(v.z); o.w = f2b(v.w);
  *(ushort4*)(out + i) = o;
}

// Lambda_1[s*8+b] = lC[(16s)*8+b]
__global__ void k_gather(const float* __restrict__ lC, float* __restrict__ lam0)
{
  int i = blockIdx.x * 256 + threadIdx.x;   // 256 WGs: 256 rows x 256 f4
  int r = i >> 8, e4 = (i & 255) * 4;
  int src = (r >> 3) * 128 + (r & 7);
  *(float4*)(lam0 + (size_t)r * 1024 + e4) = *(const float4*)(lC + (size_t)src * 1024 + e4);
}

extern "C" void kernel_launch(void* const* d_in, const int* in_sizes, int n_in,
                              void* d_out, int out_size, void* d_ws, size_t ws_size,
                              hipStream_t stream)
{
  (void)in_sizes; (void)n_in; (void)out_size; (void)ws_size;
  const float* x  = (const float*)d_in[0];
  const float* h0 = (const float*)d_in[1];
  const float* Wx = (const float*)d_in[2];
  const float* Wh = (const float*)d_in[3];
  const float* bv = (const float*)d_in[4];
  const float* uv = (const float*)d_in[5];

  float* out0 = (float*)d_out;
  float* hall = out0 + 16777216;

  // ---- ws: everything phase 3 reads ----
  char* ws = (char*)d_ws;
  u16*   xb    = (u16*)(ws);                  // 32 MiB [16384,1024] bf16
  u16*   Wcat  = (u16*)(ws + 33554432);       // 8 MiB [1024,4096]: W4|W3|W2|W1
  u16*   Xcat  = (u16*)(ws + 41943040);       // 8 MiB [1024,4096]: B3|B2|B1|B0
  u16*   bnd_b = (u16*)(ws + 50331648);       // 8 MiB [4096,1024] chunk boundaries
  float* bq    = (float*)(ws + 58720256);     // 16 KiB [4,1024]
  float* u_cur = (float*)(ws + 58736640);
  float* v_cur = u_cur + 1024;
  float* v_acc = u_cur + 2048;
  float* u_acc = u_cur + 3072;
  float* scale = u_cur + 4096;

  // ---- hall-region scratch (dead before phase 3; skips hall row 0) ----
  char* HBS = (char*)hall + 65536;
  const size_t M1 = 1048576;
  u16* wh_b = (u16*)(HBS);
  u16* whT  = (u16*)(HBS + 2*M1);
  u16* wxT  = (u16*)(HBS + 4*M1);
  u16* W2   = (u16*)(HBS + 6*M1);
  u16* W2T  = (u16*)(HBS + 8*M1);
  u16* W3p  = (u16*)(HBS + 10*M1);
  u16* W4p  = (u16*)(HBS + 12*M1);
  u16* W4T  = (u16*)(HBS + 14*M1);
  u16* W8   = (u16*)(HBS + 16*M1);
  u16* W8T  = (u16*)(HBS + 18*M1);
  u16* W12  = (u16*)(HBS + 20*M1);
  u16* W16  = (u16*)(HBS + 22*M1);
  u16* W16T = (u16*)(HBS + 24*M1);
  u16* W32  = (u16*)(HBS + 26*M1);
  u16* W32T = (u16*)(HBS + 28*M1);
  u16* W64  = (u16*)(HBS + 30*M1);
  u16* W64T = (u16*)(HBS + 32*M1);
  u16* W128 = (u16*)(HBS + 34*M1);
  u16* W128T= (u16*)(HBS + 36*M1);
  u16* W192 = (u16*)(HBS + 38*M1);
  u16* W256 = (u16*)(HBS + 40*M1);
  float* lC   = (float*)(HBS + 42*M1);        // 16 MiB [4096,1024] fp32
  float* lam0 = (float*)(HBS + 58*M1);
  float* lam1 = (float*)(HBS + 59*M1);
  float* bndS = (float*)(HBS + 60*M1);        // [256,1024] rows s*8+b
  float* pcA  = (float*)(HBS + 61*M1);
  float* pcB  = (float*)(HBS + 62*M1);

  SqCfg Z = {};

  k_init<<<32, 256, 0, stream>>>(uv, h0, u_cur, v_acc, u_acc, hall, bndS, bnd_b);

  for (int it = 0; it < 3; ++it) {
    k_v<<<dim3(4, 16), 256, 0, stream>>>(Wh, u_cur, v_acc);
    k_norm<<<1, 1024, 0, stream>>>(v_acc, v_cur, u_acc);
    k_u<<<dim3(2, 64), 256, 0, stream>>>(Wh, v_cur, u_acc);
    if (it < 2) k_norm<<<1, 1024, 0, stream>>>(u_acc, u_cur, v_acc);
    else        k_sigma<<<1, 1024, 0, stream>>>(u_acc, scale);
  }
  k_prep<<<4096, 256, 0, stream>>>(Wh, Wx, scale, wh_b, whT, wxT, Wcat, Xcat);
  k_bq<<<1, 1024, 0, stream>>>(bv, wh_b, bq);
  k_cvt<<<16384, 256, 0, stream>>>(x, xb, 16777216);

  // ---- weight prep: 8 z-batched squaring GEMMs ----
  auto sq_launch = [&](SqCfg c, int nz) {
    gX<1><<<dim3(16, 16, nz), 256, 0, stream>>>(nullptr, nullptr, nullptr, nullptr,
                                                nullptr, nullptr, nullptr, nullptr, c);
  };
  { SqCfg c = Z; c.A0=wh_b; c.B0=whT; c.o10=W2; c.t0=W2T; c.c0=Wcat+2048;
                 c.A1=wh_b; c.B1=wxT; c.c1=Xcat+2048;                       sq_launch(c,2); }
  { SqCfg c = Z; c.A0=W2; c.B0=whT; c.o10=W3p; c.c0=Wcat+1024;
                 c.A1=W2; c.B1=W2T; c.o11=W4p; c.t1=W4T; c.c1=Wcat;
                 c.A2=W2; c.B2=wxT; c.c2=Xcat+1024;                         sq_launch(c,3); }
  { SqCfg c = Z; c.A0=W3p; c.B0=wxT; c.c0=Xcat;
                 c.A1=W4p; c.B1=W4T; c.o11=W8; c.t1=W8T;                    sq_launch(c,2); }
  { SqCfg c = Z; c.A0=W8; c.B0=W4T; c.o10=W12;
                 c.A1=W8; c.B1=W8T; c.o11=W16; c.t1=W16T;                   sq_launch(c,2); }
  { SqCfg c = Z; c.A0=W16; c.B0=W16T; c.o10=W32; c.t0=W32T;                 sq_launch(c,1); }
  { SqCfg c = Z; c.A0=W32; c.B0=W32T; c.o10=W64; c.t0=W64T;                 sq_launch(c,1); }
  { SqCfg c = Z; c.A0=W64; c.B0=W64T; c.o10=W128; c.t0=W128T;               sq_launch(c,1); }
  { SqCfg c = Z; c.A0=W128; c.B0=W64T; c.o10=W192;
                 c.A1=W128; c.B1=W128T; c.o11=W256;                         sq_launch(c,2); }

  // ---- phase 1: ONE GEMM -> lC (all 512 chunk-local finals) ----
  gX<0><<<dim3(16, 64), 256, 0, stream>>>(xb, nullptr, nullptr, Xcat, bq, lC,
                                          nullptr, nullptr, Z);

  // ---- phase 2 ----
  k_gather<<<256, 256, 0, stream>>>(lC, lam0);

  // 2a: Lambda quad chain (4 launches, M=256)
  auto mk2a = [&](const float* vin, float* vout, const u16* wc,
                  const u16* w0, const u16* w1, const u16* w2,
                  int j0, int nterm) {
    MvzArgs a = {};
    a.z0.vin = vin; a.z0.Wc = wc; a.z0.nterm = nterm; a.z0.xmap = 1; a.z0.omap = 1;
    a.z0.Wt0 = w0; a.z0.xt0 = lC + (size_t)(j0    ) * 8192;
    a.z0.Wt1 = w1; a.z0.xt1 = lC + (size_t)(j0 + 1) * 8192;
    a.z0.Wt2 = w2; a.z0.xt2 = lC + (size_t)(j0 + 2) * 8192;
    if (nterm > 3) { a.z0.Wt3 = nullptr; a.z0.xt3 = lC + (size_t)(j0 + 3) * 8192; }
    a.z0.vout = vout; a.z0.outb = nullptr;
    mvz<<<dim3(64, 32, 1), 256, 0, stream>>>(a);
  };
  mk2a(lam0, lam1, W16, W12, W8, W4p, 1, 4);
  mk2a(lam1, lam0, W16, W12, W8, W4p, 5, 4);
  mk2a(lam0, lam1, W16, W12, W8, W4p, 9, 4);
  { MvzArgs a = {};   // Lambda16 = W12*L13 + W8*lC13 + W4*lC14 + lC15
    a.z0.vin = lam1; a.z0.Wc = W12; a.z0.nterm = 3; a.z0.xmap = 1; a.z0.omap = 1;
    a.z0.Wt0 = W8;  a.z0.xt0 = lC + (size_t)13 * 8192;
    a.z0.Wt1 = W4p; a.z0.xt1 = lC + (size_t)14 * 8192;
    a.z0.Wt2 = nullptr; a.z0.xt2 = lC + (size_t)15 * 8192;
    a.z0.vout = lam0;
    mvz<<<dim3(64, 32, 1), 256, 0, stream>>>(a); }

  // 2b: superchunk chain over 32 supers (8 z-quad launches, M=8)
  const u16* w64s[4] = { W64, W128, W192, W256 };
  for (int sb2 = 0; sb2 < 32; sb2 += 4) {
    int zmax = (sb2 == 28) ? 3 : 4;
    MvzArgs a = {};
    MvCfg* cz[4] = { &a.z0, &a.z1, &a.z2, &a.z3 };
    for (int zz = 1; zz <= zmax; ++zz) {
      MvCfg& c = *cz[zz - 1];
      c.vin = bndS + (size_t)sb2 * 8192;
      c.Wc = w64s[zz - 1];
      c.nterm = zz; c.xmap = 0; c.omap = 0;
      const u16* wt[4] = { nullptr, nullptr, nullptr, nullptr };
      const float* xt[4] = { nullptr, nullptr, nullptr, nullptr };
      for (int i = 0; i < zz; ++i) {
        wt[i] = (i < zz - 1) ? w64s[zz - 1 - i - 1] : nullptr;
        xt[i] = lam0 + (size_t)(sb2 + i) * 8192;
      }
      c.Wt0 = wt[0]; c.Wt1 = wt[1]; c.Wt2 = wt[2]; c.Wt3 = wt[3];
      c.xt0 = xt[0]; c.xt1 = xt[1]; c.xt2 = xt[2]; c.xt3 = xt[3];
      c.vout = bndS + (size_t)(sb2 + zz) * 8192;
      c.outb = bnd_b + (size_t)16 * (sb2 + zz) * 8192;
    }
    mvz<<<dim3(64, 1, zmax), 256, 0, stream>>>(a);
  }

  // 2c: recover intra-super chunk boundaries (4 z-quad launches, M=256)
  const u16* w4s[4] = { W4p, W8, W12, W16 };
  const float* vins[4] = { bndS, pcA, pcB, pcA };
  float* vouts[4] = { pcA, pcB, pcA, nullptr };
  for (int t4 = 0; t4 < 4; ++t4) {
    int jb = t4 * 4;
    int zmax = (jb == 12) ? 3 : 4;
    MvzArgs a = {};
    MvCfg* cz[4] = { &a.z0, &a.z1, &a.z2, &a.z3 };
    for (int zz = 1; zz <= zmax; ++zz) {
      MvCfg& c = *cz[zz - 1];
      c.vin = vins[t4];
      c.Wc = w4s[zz - 1];
      c.nterm = zz; c.xmap = 1; c.omap = 1;
      const u16* wt[4] = { nullptr, nullptr, nullptr, nullptr };
      const float* xt[4] = { nullptr, nullptr, nullptr, nullptr };
      for (int i = 0; i < zz; ++i) {
        wt[i] = (i < zz - 1) ? w4s[zz - 1 - i - 1] : nullptr;
        xt[i] = lC + (size_t)(jb + i) * 8192;
      }
      c.Wt0 = wt[0]; c.Wt1 = wt[1]; c.Wt2 = wt[2]; c.Wt3 = wt[3];
      c.xt0 = xt[0]; c.xt1 = xt[1]; c.xt2 = xt[2]; c.xt3 = xt[3];
      c.vout = (zz == 4) ? vouts[t4] : nullptr;
      c.outb = bnd_b + (size_t)(jb + zz) * 8192;
    }
    mvz<<<dim3(64, 32, zmax), 256, 0, stream>>>(a);
  }

  // ---- phase 3: ONE z-batched GEMM -> h_all + h^2*silu ----
  gX<3><<<dim3(16, 64, 4), 256, 0, stream>>>(xb, bnd_b, Wcat, Xcat, bq, nullptr,
                                             hall, out0, Z);
}

// Round 9
// 1341.343 us; speedup vs baseline: 1.7547x; 1.7547x over previous
//
#include <hip/hip_runtime.h>
#include <hip/hip_bf16.h>

#define DEV __device__ __forceinline__

typedef __bf16 bf16x8 __attribute__((ext_vector_type(8)));
typedef float  f32x4  __attribute__((ext_vector_type(4)));
typedef unsigned short u16;

DEV u16   f2b(float f) { __bf16 h = (__bf16)f; return __builtin_bit_cast(u16, h); }
DEV float b2f(u16 x)   { return __builtin_bit_cast(float, ((unsigned)x) << 16); }

DEV void gl_lds16(const u16* g, u16* l) {
  __builtin_amdgcn_global_load_lds((const __attribute__((address_space(1))) void*)g,
                                   (__attribute__((address_space(3))) void*)l, 16, 0, 0);
}

// row map: S>0 -> ((m>>3)*S + j)*8 + (m&7)  (chunk-spread layouts; S=4 x/t, S=16 super)
//          S==0 -> m (plain)     S<0 -> m&7 (replicate 8-row slab)
DEV long arow(int m, int S, int j) {
  if (S > 0)  return ((long)((m >> 3) * S + j)) * 8 + (m & 7);
  if (S == 0) return m;
  return m & 7;
}

// ---------------------------------------------------------------------------
// Unified segment-GEMM: D[m,e] = sum_{seg} sum_d A_seg[map(m),d] * B_seg[e,d]
// (64x64 tile, BK=128 double-buffered LDS, proven R7/R8 core). Up to 5 segs.
// MODE 0: squaring (bf16 out + optional transpose)
// MODE 1: phase1   (+= addc[col]; fp32 outf + bf16 outb)
// MODE 2: phase2   (+= addf[map]; hi/lo bf16 chain out + mapped bf16 out)
// MODE 3: phase3   (+= addc[col]; hall[t] fp32 + out0[t-1] = h^2*sigmoid(h))
// ---------------------------------------------------------------------------
struct ZCfg {
  const u16 *A0, *A1, *A2, *A3, *A4;
  const u16 *B0, *B1, *B2, *B3, *B4;
  int S0, J0, S1, J1, S2, J2, S3, J3, S4, J4;
  int nseg, mvalid, q;
  const float* addc;                 // per-col add (bq row)
  const float* addf; int addS, addJ; // mapped fp32 add (identity term)
  float* outf;
  u16 *outb, *outbT, *outlo;
  u16* outm; int oS, oJ;             // mapped bf16 out (bnd_b)
  float *hall, *out0;
};
struct GArgs { ZCfg z0, z1, z2, z3; };

template<int MODE>
__global__ __launch_bounds__(256) void gU(GArgs ga)
{
  ZCfg c;
  switch (blockIdx.z) { case 0: c = ga.z0; break; case 1: c = ga.z1; break;
                        case 2: c = ga.z2; break; default: c = ga.z3; break; }
  const int K = c.nseg << 10;

  int tid = threadIdx.x, lane = tid & 63, w = tid >> 6;
  int wrow = (w >> 1) << 5, wcol = (w & 1) << 5;
  int m0 = blockIdx.y << 6, e0 = blockIdx.x << 6;

  __shared__ u16 As[2][8192], Bs[2][8192];
  f32x4 acc[2][2] = {};

  int rA[4], cA[4];
#pragma unroll
  for (int j = 0; j < 4; ++j) {
    int p = (j * 4 + w) * 1024 + lane * 16;
    int r = p >> 8, o = (p & 255) ^ ((r & 7) << 4);
    rA[j] = r; cA[j] = o >> 1;
  }
  auto seg = [&](int i, const u16*& A, int& S, int& J, const u16*& B) {
    switch (i) {
      case 0: A = c.A0; S = c.S0; J = c.J0; B = c.B0; break;
      case 1: A = c.A1; S = c.S1; J = c.J1; B = c.B1; break;
      case 2: A = c.A2; S = c.S2; J = c.J2; B = c.B2; break;
      case 3: A = c.A3; S = c.S3; J = c.J3; B = c.B3; break;
      default: A = c.A4; S = c.S4; J = c.J4; B = c.B4; break;
    }
  };
  auto stage = [&](int buf, int kt) {
    int si = kt >> 10, kl = kt & 1023;
    const u16 *A, *B; int S, J;
    seg(si, A, S, J, B);
#pragma unroll
    for (int j = 0; j < 4; ++j) {
      int grow = m0 + rA[j];
      gl_lds16(A + arow(grow, S, J) * 1024 + kl + cA[j], &As[buf][(j * 4 + w) * 512]);
    }
#pragma unroll
    for (int j = 0; j < 4; ++j)
      gl_lds16(B + (size_t)(e0 + rA[j]) * 1024 + kl + cA[j], &Bs[buf][(j * 4 + w) * 512]);
  };

  stage(0, 0);
  asm volatile("s_waitcnt vmcnt(0)" ::: "memory");
  __syncthreads();

  int buf = 0;
  for (int kt = 0; kt < K; kt += 128, buf ^= 1) {
    if (kt + 128 < K) stage(buf ^ 1, kt + 128);
#pragma unroll
    for (int ks = 0; ks < 4; ++ks) {
      int oa = ks * 64 + ((lane >> 4) << 4);
      bf16x8 af[2], bf[2];
#pragma unroll
      for (int s = 0; s < 2; ++s) {
        int ra = wrow + s * 16 + (lane & 15);
        int rb = wcol + s * 16 + (lane & 15);
        af[s] = *(const bf16x8*)((const char*)&As[buf][0] + ra * 256 + (oa ^ ((ra & 7) << 4)));
        bf[s] = *(const bf16x8*)((const char*)&Bs[buf][0] + rb * 256 + (oa ^ ((rb & 7) << 4)));
      }
#pragma unroll
      for (int ms = 0; ms < 2; ++ms)
#pragma unroll
        for (int ns = 0; ns < 2; ++ns)
          acc[ms][ns] = __builtin_amdgcn_mfma_f32_16x16x32_bf16(af[ms], bf[ns], acc[ms][ns], 0, 0, 0);
    }
    asm volatile("s_waitcnt vmcnt(0)" ::: "memory");
    __syncthreads();
  }

  int l4 = ((lane >> 4) << 2), lc = lane & 15;
#pragma unroll
  for (int ms = 0; ms < 2; ++ms)
#pragma unroll
    for (int ns = 0; ns < 2; ++ns)
#pragma unroll
      for (int j = 0; j < 4; ++j) {
        int row = m0 + wrow + ms * 16 + l4 + j;   // C/D: row=(lane>>4)*4+reg
        int col = e0 + wcol + ns * 16 + lc;       // C/D: col=lane&15
        float v = acc[ms][ns][j];
        if (MODE == 0) {
          u16 h = f2b(v);
          if (c.outb)  c.outb[(size_t)row * 1024 + col] = h;
          if (c.outbT) c.outbT[(size_t)col * 1024 + row] = h;
        } else if (MODE == 1) {
          v += c.addc[col];
          c.outf[(size_t)row * 1024 + col] = v;
          c.outb[(size_t)row * 1024 + col] = f2b(v);
        } else if (MODE == 2) {
          if (c.addf) v += c.addf[arow(row, c.addS, c.addJ) * 1024 + col];
          if (row < c.mvalid) {
            if (c.outf) c.outf[(size_t)row * 1024 + col] = v;
            u16 hi = f2b(v);
            if (c.outb)  c.outb[(size_t)row * 1024 + col] = hi;
            if (c.outlo) c.outlo[(size_t)row * 1024 + col] = f2b(v - b2f(hi));
            if (c.outm)  c.outm[arow(row, c.oS, c.oJ) * 1024 + col] = hi;
          }
        } else {
          v += c.addc[col];
          int t = (row >> 3) * 4 + c.q, b = row & 7;
          c.hall[(size_t)t * 8192 + b * 1024 + col] = v;
          float sg = 1.f / (1.f + __expf(-v));
          c.out0[(size_t)(t - 1) * 8192 + b * 1024 + col] = v * v * sg;
        }
      }
}

// ---- power iteration + misc helpers (R8-proven) ----------------------------
__global__ void k_init(const float* __restrict__ u_in, const float* __restrict__ h0,
                       float* __restrict__ u_cur, float* __restrict__ v_acc,
                       float* __restrict__ u_acc, float* __restrict__ hall0,
                       float* __restrict__ bndS, u16* __restrict__ bndSb,
                       u16* __restrict__ bndSlo, u16* __restrict__ bndb)
{
  int i = blockIdx.x * 256 + threadIdx.x;
  if (i < 1024) { u_cur[i] = u_in[i]; v_acc[i] = 0.f; u_acc[i] = 0.f; }
  if (i < 8192) {
    float h = h0[i];
    hall0[i] = h;
    bndS[i] = h;
    u16 hi = f2b(h);
    bndSb[i] = hi;
    bndSlo[i] = f2b(h - b2f(hi));
    bndb[i] = hi;              // bnd_b chunk 0
  }
}

__global__ void k_v(const float* __restrict__ W, const float* __restrict__ u_cur,
                    float* __restrict__ v_acc)
{
  int d = blockIdx.x * 256 + threadIdx.x;
  int e0 = blockIdx.y * 64;
  float a = 0.f;
  for (int e = e0; e < e0 + 64; ++e) a += W[(size_t)e * 1024 + d] * u_cur[e];
  atomicAdd(&v_acc[d], a);
}

__global__ void k_u(const float* __restrict__ W, const float* __restrict__ v_cur,
                    float* __restrict__ u_acc)
{
  int lg = threadIdx.x & 15, ei = threadIdx.x >> 4;
  int e = blockIdx.y * 16 + ei;
  int d0 = blockIdx.x * 512;
  float a = 0.f;
  for (int i = 0; i < 32; ++i) { int d = d0 + lg + 16 * i; a += W[(size_t)e * 1024 + d] * v_cur[d]; }
#pragma unroll
  for (int m = 1; m < 16; m <<= 1) a += __shfl_xor(a, m);
  if (lg == 0) atomicAdd(&u_acc[e], a);
}

__global__ void k_norm(const float* __restrict__ acc, float* __restrict__ outv,
                       float* __restrict__ z1)
{
  __shared__ float red[16];
  int t = threadIdx.x;
  float x = acc[t];
  float ss = x * x;
#pragma unroll
  for (int m = 1; m < 64; m <<= 1) ss += __shfl_xor(ss, m);
  if ((t & 63) == 0) red[t >> 6] = ss;
  __syncthreads();
  if (t < 64) {
    float s = (t < 16) ? red[t] : 0.f;
#pragma unroll
    for (int m = 1; m < 16; m <<= 1) s += __shfl_xor(s, m);
    if (t == 0) red[0] = s;
  }
  __syncthreads();
  float nrm = sqrtf(red[0]) + 1e-8f;
  outv[t] = x / nrm;
  z1[t] = 0.f;
}

__global__ void k_sigma(const float* __restrict__ acc, float* __restrict__ scale)
{
  __shared__ float red[16];
  int t = threadIdx.x;
  float x = acc[t];
  float ss = x * x;
#pragma unroll
  for (int m = 1; m < 64; m <<= 1) ss += __shfl_xor(ss, m);
  if ((t & 63) == 0) red[t >> 6] = ss;
  __syncthreads();
  if (t < 64) {
    float s = (t < 16) ? red[t] : 0.f;
#pragma unroll
    for (int m = 1; m < 16; m <<= 1) s += __shfl_xor(s, m);
    if (t == 0) {
      float sigma = s / (sqrtf(s) + 1e-8f);
      scale[0] = 0.95f / (sigma + 1e-8f);
    }
  }
}

// Wh*scale -> wh_b, whT; Wx -> wxb, wxT
__global__ void k_prep(const float* __restrict__ Wh, const float* __restrict__ Wx,
                       const float* __restrict__ scale, u16* __restrict__ wh_b,
                       u16* __restrict__ whT, u16* __restrict__ wxb,
                       u16* __restrict__ wxT)
{
  int i = blockIdx.x * 256 + threadIdx.x;
  float s = scale[0];
  int e = i >> 10, d = i & 1023;
  u16 hw = f2b(Wh[i] * s), hx = f2b(Wx[i]);
  wh_b[i] = hw;
  whT[(size_t)d * 1024 + e] = hw;
  wxb[i] = hx;
  wxT[(size_t)d * 1024 + e] = hx;
}

// bq[q-1] = (sum_{j<q} W^j) b, q=1..4
__global__ void k_bq(const float* __restrict__ b, const u16* __restrict__ wh,
                     float* __restrict__ bq)
{
  __shared__ float sb[1024];
  int e = threadIdx.x;
  float cur = b[e];
  bq[e] = cur;
  for (int qq = 2; qq <= 4; ++qq) {
    sb[e] = cur;
    __syncthreads();
    float a = 0.f;
    for (int d = 0; d < 1024; ++d) a += b2f(wh[(size_t)e * 1024 + d]) * sb[d];
    cur = a + b[e];
    bq[(qq - 1) * 1024 + e] = cur;
    __syncthreads();
  }
}

__global__ void k_cvt(const float* __restrict__ in, u16* __restrict__ out, int n)
{
  int i = (blockIdx.x * 256 + threadIdx.x) * 4;
  if (i >= n) return;
  float4 v = *(const float4*)(in + i);
  ushort4 o;
  o.x = f2b(v.x); o.y = f2b(v.y); o.z = f2b(v.z); o.w = f2b(v.w);
  *(ushort4*)(out + i) = o;
}

// Lambda_1 (hi/lo) from lC chunk s*16
__global__ void k_gather(const float* __restrict__ lC, u16* __restrict__ lamH,
                         u16* __restrict__ lamL)
{
  int i = blockIdx.x * 256 + threadIdx.x;   // 256 WGs, 256 rows x 256 f4
  int r = i >> 8, e4 = (i & 255) * 4;
  int src = (r >> 3) * 128 + (r & 7);
  float4 v = *(const float4*)(lC + (size_t)src * 1024 + e4);
  ushort4 hi, lo;
  hi.x = f2b(v.x); lo.x = f2b(v.x - b2f(hi.x));
  hi.y = f2b(v.y); lo.y = f2b(v.y - b2f(hi.y));
  hi.z = f2b(v.z); lo.z = f2b(v.z - b2f(hi.z));
  hi.w = f2b(v.w); lo.w = f2b(v.w - b2f(hi.w));
  *(ushort4*)(lamH + (size_t)r * 1024 + e4) = hi;
  *(ushort4*)(lamL + (size_t)r * 1024 + e4) = lo;
}

static void setseg(ZCfg& z, int i, const u16* A, int S, int J, const u16* B) {
  switch (i) {
    case 0: z.A0 = A; z.S0 = S; z.J0 = J; z.B0 = B; break;
    case 1: z.A1 = A; z.S1 = S; z.J1 = J; z.B1 = B; break;
    case 2: z.A2 = A; z.S2 = S; z.J2 = J; z.B2 = B; break;
    case 3: z.A3 = A; z.S3 = S; z.J3 = J; z.B3 = B; break;
    default: z.A4 = A; z.S4 = S; z.J4 = J; z.B4 = B; break;
  }
}

extern "C" void kernel_launch(void* const* d_in, const int* in_sizes, int n_in,
                              void* d_out, int out_size, void* d_ws, size_t ws_size,
                              hipStream_t stream)
{
  (void)in_sizes; (void)n_in; (void)out_size; (void)ws_size;
  const float* x  = (const float*)d_in[0];
  const float* h0 = (const float*)d_in[1];
  const float* Wx = (const float*)d_in[2];
  const float* Wh = (const float*)d_in[3];
  const float* bv = (const float*)d_in[4];
  const float* uv = (const float*)d_in[5];

  float* out0 = (float*)d_out;
  float* hall = out0 + 16777216;

  // ---- ws: everything phase 3 reads ----
  char* ws = (char*)d_ws;
  const size_t M1 = 1048576;
  u16*   xb    = (u16*)(ws);                  // 32 MiB [16384,1024]
  u16*   wh_b  = (u16*)(ws + 32 * M1);        // W^1
  u16*   W2    = (u16*)(ws + 34 * M1);
  u16*   W3    = (u16*)(ws + 36 * M1);
  u16*   W4    = (u16*)(ws + 38 * M1);
  u16*   Bx0   = (u16*)(ws + 40 * M1);        // Wx
  u16*   Bx1   = (u16*)(ws + 42 * M1);        // W Wx
  u16*   Bx2   = (u16*)(ws + 44 * M1);        // W^2 Wx
  u16*   Bx3   = (u16*)(ws + 46 * M1);        // W^3 Wx
  u16*   bnd_b = (u16*)(ws + 48 * M1);        // 8 MiB [4096,1024] chunk boundaries
  float* bq    = (float*)(ws + 56 * M1);      // [4,1024]
  float* u_cur = (float*)(ws + 56 * M1 + 16384);
  float* v_cur = u_cur + 1024;
  float* v_acc = u_cur + 2048;
  float* u_acc = u_cur + 3072;
  float* scale = u_cur + 4096;

  // ---- hall-region scratch (dead before phase 3; skips hall row 0) ----
  char* HBS = (char*)hall + 32768;
  u16* whT   = (u16*)(HBS);
  u16* wxT   = (u16*)(HBS + 2 * M1);
  u16* W2T   = (u16*)(HBS + 4 * M1);          // later reused as W192
  u16* W4T   = (u16*)(HBS + 6 * M1);
  u16* W8    = (u16*)(HBS + 8 * M1);
  u16* W8T   = (u16*)(HBS + 10 * M1);
  u16* W12   = (u16*)(HBS + 12 * M1);
  u16* W16   = (u16*)(HBS + 14 * M1);
  u16* W16T  = (u16*)(HBS + 16 * M1);
  u16* W32   = (u16*)(HBS + 18 * M1);
  u16* W32T  = (u16*)(HBS + 20 * M1);
  u16* W64   = (u16*)(HBS + 22 * M1);
  u16* W64T  = (u16*)(HBS + 24 * M1);
  u16* W128  = (u16*)(HBS + 26 * M1);
  u16* W128T = (u16*)(HBS + 28 * M1);
  u16* W256  = (u16*)(HBS + 30 * M1);
  u16* W192  = W2T;                            // alias: W2T dead after L2
  float* lC  = (float*)(HBS + 32 * M1);       // 16 MiB [4096,1024] fp32
  u16* lCb   = (u16*)(HBS + 48 * M1);         // 8 MiB bf16
  float* lamF = (float*)(HBS + 56 * M1);      // [256,1024] fp32
  u16* lamH0 = (u16*)(HBS + 57 * M1);
  u16* lamH1 = (u16*)(HBS + 57 * M1 + 524288);
  u16* lamL0 = (u16*)(HBS + 58 * M1);
  u16* lamL1 = (u16*)(HBS + 58 * M1 + 524288);
  float* bndS = (float*)(HBS + 59 * M1);      // [256,1024] fp32 (init only)
  u16* bndSb  = (u16*)(HBS + 60 * M1);
  u16* bndSlo = (u16*)(HBS + 60 * M1 + 524288);
  u16* pcH0 = (u16*)(HBS + 61 * M1);
  u16* pcH1 = (u16*)(HBS + 61 * M1 + 524288);
  u16* pcL0 = (u16*)(HBS + 62 * M1);
  u16* pcL1 = (u16*)(HBS + 62 * M1 + 524288);

  k_init<<<32, 256, 0, stream>>>(uv, h0, u_cur, v_acc, u_acc, hall, bndS,
                                 bndSb, bndSlo, bnd_b);

  for (int it = 0; it < 3; ++it) {
    k_v<<<dim3(4, 16), 256, 0, stream>>>(Wh, u_cur, v_acc);
    k_norm<<<1, 1024, 0, stream>>>(v_acc, v_cur, u_acc);
    k_u<<<dim3(2, 64), 256, 0, stream>>>(Wh, v_cur, u_acc);
    if (it < 2) k_norm<<<1, 1024, 0, stream>>>(u_acc, u_cur, v_acc);
    else        k_sigma<<<1, 1024, 0, stream>>>(u_acc, scale);
  }
  k_prep<<<4096, 256, 0, stream>>>(Wh, Wx, scale, wh_b, whT, Bx0, wxT);
  k_bq<<<1, 1024, 0, stream>>>(bv, wh_b, bq);
  k_cvt<<<16384, 256, 0, stream>>>(x, xb, 16777216);

  auto sqz = [](ZCfg& z, const u16* A, const u16* B, u16* o, u16* oT) {
    z.A0 = A; z.S0 = 0; z.J0 = 0; z.B0 = B; z.nseg = 1; z.outb = o; z.outbT = oT;
  };
  // ---- Wh powers: 8 z-batched squaring launches ----
  { GArgs a{}; sqz(a.z0, wh_b, whT, W2, W2T); sqz(a.z1, wh_b, wxT, Bx1, nullptr);
    gU<0><<<dim3(16, 16, 2), 256, 0, stream>>>(a); }
  { GArgs a{}; sqz(a.z0, W2, whT, W3, nullptr); sqz(a.z1, W2, W2T, W4, W4T);
    sqz(a.z2, W2, wxT, Bx2, nullptr);
    gU<0><<<dim3(16, 16, 3), 256, 0, stream>>>(a); }
  { GArgs a{}; sqz(a.z0, W3, wxT, Bx3, nullptr); sqz(a.z1, W4, W4T, W8, W8T);
    gU<0><<<dim3(16, 16, 2), 256, 0, stream>>>(a); }
  { GArgs a{}; sqz(a.z0, W8, W4T, W12, nullptr); sqz(a.z1, W8, W8T, W16, W16T);
    gU<0><<<dim3(16, 16, 2), 256, 0, stream>>>(a); }
  { GArgs a{}; sqz(a.z0, W16, W16T, W32, W32T);
    gU<0><<<dim3(16, 16, 1), 256, 0, stream>>>(a); }
  { GArgs a{}; sqz(a.z0, W32, W32T, W64, W64T);
    gU<0><<<dim3(16, 16, 1), 256, 0, stream>>>(a); }
  { GArgs a{}; sqz(a.z0, W64, W64T, W128, W128T);
    gU<0><<<dim3(16, 16, 1), 256, 0, stream>>>(a); }
  { GArgs a{}; sqz(a.z0, W128, W64T, W192, nullptr); sqz(a.z1, W128, W128T, W256, nullptr);
    gU<0><<<dim3(16, 16, 2), 256, 0, stream>>>(a); }

  // ---- phase 1: ONE GEMM -> lC fp32 + lCb bf16 (all 512 chunk-local finals)
  { GArgs a{}; ZCfg& z = a.z0;
    setseg(z, 0, xb, 4, 0, Bx3); setseg(z, 1, xb, 4, 1, Bx2);
    setseg(z, 2, xb, 4, 2, Bx1); setseg(z, 3, xb, 4, 3, Bx0);
    z.nseg = 4; z.addc = bq + 3072; z.outf = lC; z.outb = lCb;
    gU<1><<<dim3(16, 64, 1), 256, 0, stream>>>(a); }

  // ---- phase 2a: Lambda chain (gather + 3 quad + 1 final) ----
  k_gather<<<256, 256, 0, stream>>>(lC, lamH0, lamL0);
  {
    const u16 *chH = lamH0, *chL = lamL0;
    int j0s[3] = {1, 5, 9};
    int pp = 1;
    for (int i = 0; i < 3; ++i) {
      u16* nxH = pp ? lamH1 : lamH0;
      u16* nxL = pp ? lamL1 : lamL0;
      GArgs a{}; ZCfg& z = a.z0;
      setseg(z, 0, chH, 0, 0, W16); setseg(z, 1, chL, 0, 0, W16);
      setseg(z, 2, lCb, 16, j0s[i],     W12);
      setseg(z, 3, lCb, 16, j0s[i] + 1, W8);
      setseg(z, 4, lCb, 16, j0s[i] + 2, W4);
      z.nseg = 5; z.mvalid = 256;
      z.addf = lC; z.addS = 16; z.addJ = j0s[i] + 3;
      z.outb = nxH; z.outlo = nxL;
      gU<2><<<dim3(16, 4, 1), 256, 0, stream>>>(a);
      chH = nxH; chL = nxL; pp ^= 1;
    }
    GArgs a{}; ZCfg& z = a.z0;   // Lambda16 = W12*L13 + W8 lC13 + W4 lC14 + lC15
    setseg(z, 0, chH, 0, 0, W12); setseg(z, 1, chL, 0, 0, W12);
    setseg(z, 2, lCb, 16, 13, W8); setseg(z, 3, lCb, 16, 14, W4);
    z.nseg = 4; z.mvalid = 256;
    z.addf = lC; z.addS = 16; z.addJ = 15;
    z.outf = lamF; z.outb = lamH0; z.outlo = lamL0;
    gU<2><<<dim3(16, 4, 1), 256, 0, stream>>>(a);
  }

  // ---- phase 2b: superchunk chain, 8 z-quad launches (M=8) ----
  {
    const u16* w64s[4] = { W64, W128, W192, W256 };
    for (int sb2 = 0; sb2 < 32; sb2 += 4) {
      int zmax = (sb2 == 28) ? 3 : 4;
      GArgs a{};
      ZCfg* zs[4] = { &a.z0, &a.z1, &a.z2, &a.z3 };
      for (int zz = 1; zz <= zmax; ++zz) {
        ZCfg& z = *zs[zz - 1];
        setseg(z, 0, bndSb + (size_t)sb2 * 8192, -1, 0, w64s[zz - 1]);
        int ns = 1;
        for (int i = 0; i < zz - 1; ++i)
          setseg(z, ns++, lamH0 + (size_t)(sb2 + i) * 8192, -1, 0, w64s[zz - 2 - i]);
        z.nseg = ns; z.mvalid = 8;
        z.addf = lamF + (size_t)(sb2 + zz - 1) * 8192; z.addS = -1;
        z.outb = bndSb + (size_t)(sb2 + zz) * 8192;
        z.outlo = bndSlo + (size_t)(sb2 + zz) * 8192;
        z.outm = bnd_b + (size_t)16 * (sb2 + zz) * 8192; z.oS = 0;
      }
      gU<2><<<dim3(16, 1, zmax), 256, 0, stream>>>(a);
    }
  }

  // ---- phase 2c: intra-super chunk boundaries, 4 z-quad launches (M=256) ----
  {
    const u16* w4s[4] = { W4, W8, W12, W16 };
    const u16* cinH[4] = { bndSb, pcH0, pcH1, pcH0 };
    const u16* cinL[4] = { bndSlo, pcL0, pcL1, pcL0 };
    u16* coutH[4] = { pcH0, pcH1, pcH0, nullptr };
    u16* coutL[4] = { pcL0, pcL1, pcL0, nullptr };
    for (int t4 = 0; t4 < 4; ++t4) {
      int jb = 4 * t4;
      int zmax = (t4 == 3) ? 3 : 4;
      GArgs a{};
      ZCfg* zs[4] = { &a.z0, &a.z1, &a.z2, &a.z3 };
      for (int zz = 1; zz <= zmax; ++zz) {
        ZCfg& z = *zs[zz - 1];
        setseg(z, 0, cinH[t4], 0, 0, w4s[zz - 1]);
        setseg(z, 1, cinL[t4], 0, 0, w4s[zz - 1]);
        int ns = 2;
        for (int i = 0; i < zz - 1; ++i)
          setseg(z, ns++, lCb, 16, jb + i, w4s[zz - 2 - i]);
        z.nseg = ns; z.mvalid = 256;
        z.addf = lC; z.addS = 16; z.addJ = jb + zz - 1;
        z.outm = bnd_b; z.oS = 16; z.oJ = jb + zz;
        if (zz == 4) { z.outb = coutH[t4]; z.outlo = coutL[t4]; }
      }
      gU<2><<<dim3(16, 4, zmax), 256, 0, stream>>>(a);
    }
  }

  // ---- phase 3: ONE z-batched GEMM -> h_all + h^2*silu ----
  {
    const u16* Wq[4]  = { wh_b, W2, W3, W4 };
    const u16* Bxs[4] = { Bx0, Bx1, Bx2, Bx3 };
    GArgs a{};
    ZCfg* zs[4] = { &a.z0, &a.z1, &a.z2, &a.z3 };
    for (int q = 1; q <= 4; ++q) {
      ZCfg& z = *zs[q - 1];
      setseg(z, 0, bnd_b, 0, 0, Wq[q - 1]);
      for (int i = 0; i < q; ++i)
        setseg(z, 1 + i, xb, 4, i, Bxs[q - 1 - i]);
      z.nseg = 1 + q; z.q = q;
      z.addc = bq + (q - 1) * 1024;
      z.hall = hall; z.out0 = out0;
    }
    gU<3><<<dim3(16, 64, 4), 256, 0, stream>>>(a);
  }
}

// Round 10
// 1094.723 us; speedup vs baseline: 2.1500x; 1.2253x over previous
//
#include <hip/hip_runtime.h>
#include <hip/hip_bf16.h>

#define DEV __device__ __forceinline__

typedef __bf16 bf16x8 __attribute__((ext_vector_type(8)));
typedef float  f32x4  __attribute__((ext_vector_type(4)));
typedef unsigned short u16;

DEV u16   f2b(float f) { __bf16 h = (__bf16)f; return __builtin_bit_cast(u16, h); }
DEV float b2f(u16 x)   { return __builtin_bit_cast(float, ((unsigned)x) << 16); }

DEV void gl_lds16(const u16* g, u16* l) {
  __builtin_amdgcn_global_load_lds((const __attribute__((address_space(1))) void*)g,
                                   (__attribute__((address_space(3))) void*)l, 16, 0, 0);
}

// row map: S>0 -> ((m>>3)*S + j)*8 + (m&7); S==0 -> m; S<0 -> m&7 (replicate)
DEV long arow(int m, int S, int j) {
  if (S > 0)  return ((long)((m >> 3) * S + j)) * 8 + (m & 7);
  if (S == 0) return m;
  return m & 7;
}

// ---------------------------------------------------------------------------
// Unified segment-GEMM: D[m,e] = sum_{seg} sum_d A_seg[map(m),d] * B_seg[e,d]
// MODE 0: squaring (bf16 out + optional transpose)
// MODE 1: pre    (+= addc[col]; fp32 outf + bf16 outb)
// MODE 2: ph1/2  (+= addf[map]; fp32 outf, hi/lo bf16, mapped bf16 out)
// MODE 3: ph3    (+= b2f(addb[map]); hall[t] fp32 + out0[t-1] + chain bf16)
// ---------------------------------------------------------------------------
struct ZCfg {
  const u16 *A0, *A1, *A2, *A3, *A4;
  const u16 *B0, *B1, *B2, *B3, *B4;
  int S0, J0, S1, J1, S2, J2, S3, J3, S4, J4;
  int nseg, mvalid, q;
  const float* addc;
  const float* addf; int addS, addJ;
  const u16* addb; int abJ;
  float* outf;
  u16 *outb, *outbT, *outlo;
  u16* outm; int oS, oJ;
  float *hall, *out0;
};
struct GArgs { ZCfg z0, z1, z2, z3; };

template<int MODE>
__global__ __launch_bounds__(256) void gU(GArgs ga)
{
  ZCfg c;
  switch (blockIdx.z) { case 0: c = ga.z0; break; case 1: c = ga.z1; break;
                        case 2: c = ga.z2; break; default: c = ga.z3; break; }
  const int K = c.nseg << 10;

  int tid = threadIdx.x, lane = tid & 63, w = tid >> 6;
  int wrow = (w >> 1) << 5, wcol = (w & 1) << 5;
  int m0 = blockIdx.y << 6, e0 = blockIdx.x << 6;

  __shared__ u16 As[2][8192], Bs[2][8192];
  f32x4 acc[2][2] = {};

  int rA[4], cA[4];
#pragma unroll
  for (int j = 0; j < 4; ++j) {
    int p = (j * 4 + w) * 1024 + lane * 16;
    int r = p >> 8, o = (p & 255) ^ ((r & 7) << 4);
    rA[j] = r; cA[j] = o >> 1;
  }
  auto seg = [&](int i, const u16*& A, int& S, int& J, const u16*& B) {
    switch (i) {
      case 0: A = c.A0; S = c.S0; J = c.J0; B = c.B0; break;
      case 1: A = c.A1; S = c.S1; J = c.J1; B = c.B1; break;
      case 2: A = c.A2; S = c.S2; J = c.J2; B = c.B2; break;
      case 3: A = c.A3; S = c.S3; J = c.J3; B = c.B3; break;
      default: A = c.A4; S = c.S4; J = c.J4; B = c.B4; break;
    }
  };
  auto stage = [&](int buf, int kt) {
    int si = kt >> 10, kl = kt & 1023;
    const u16 *A, *B; int S, J;
    seg(si, A, S, J, B);
#pragma unroll
    for (int j = 0; j < 4; ++j) {
      int grow = m0 + rA[j];
      gl_lds16(A + arow(grow, S, J) * 1024 + kl + cA[j], &As[buf][(j * 4 + w) * 512]);
    }
#pragma unroll
    for (int j = 0; j < 4; ++j)
      gl_lds16(B + (size_t)(e0 + rA[j]) * 1024 + kl + cA[j], &Bs[buf][(j * 4 + w) * 512]);
  };

  stage(0, 0);
  asm volatile("s_waitcnt vmcnt(0)" ::: "memory");
  __syncthreads();

  int buf = 0;
  for (int kt = 0; kt < K; kt += 128, buf ^= 1) {
    if (kt + 128 < K) stage(buf ^ 1, kt + 128);
#pragma unroll
    for (int ks = 0; ks < 4; ++ks) {
      int oa = ks * 64 + ((lane >> 4) << 4);
      bf16x8 af[2], bf[2];
#pragma unroll
      for (int s = 0; s < 2; ++s) {
        int ra = wrow + s * 16 + (lane & 15);
        int rb = wcol + s * 16 + (lane & 15);
        af[s] = *(const bf16x8*)((const char*)&As[buf][0] + ra * 256 + (oa ^ ((ra & 7) << 4)));
        bf[s] = *(const bf16x8*)((const char*)&Bs[buf][0] + rb * 256 + (oa ^ ((rb & 7) << 4)));
      }
#pragma unroll
      for (int ms = 0; ms < 2; ++ms)
#pragma unroll
        for (int ns = 0; ns < 2; ++ns)
          acc[ms][ns] = __builtin_amdgcn_mfma_f32_16x16x32_bf16(af[ms], bf[ns], acc[ms][ns], 0, 0, 0);
    }
    asm volatile("s_waitcnt vmcnt(0)" ::: "memory");
    __syncthreads();
  }

  int l4 = ((lane >> 4) << 2), lc = lane & 15;
#pragma unroll
  for (int ms = 0; ms < 2; ++ms)
#pragma unroll
    for (int ns = 0; ns < 2; ++ns)
#pragma unroll
      for (int j = 0; j < 4; ++j) {
        int row = m0 + wrow + ms * 16 + l4 + j;   // C/D: row=(lane>>4)*4+reg
        int col = e0 + wcol + ns * 16 + lc;       // C/D: col=lane&15
        float v = acc[ms][ns][j];
        if (MODE == 0) {
          u16 h = f2b(v);
          if (c.outb)  c.outb[(size_t)row * 1024 + col] = h;
          if (c.outbT) c.outbT[(size_t)col * 1024 + row] = h;
        } else if (MODE == 1) {
          v += c.addc[col];
          c.outf[(size_t)row * 1024 + col] = v;
          c.outb[(size_t)row * 1024 + col] = f2b(v);
        } else if (MODE == 2) {
          if (c.addf) v += c.addf[arow(row, c.addS, c.addJ) * 1024 + col];
          if (row < c.mvalid) {
            if (c.outf) c.outf[(size_t)row * 1024 + col] = v;
            u16 hi = f2b(v);
            if (c.outb)  c.outb[(size_t)row * 1024 + col] = hi;
            if (c.outlo) c.outlo[(size_t)row * 1024 + col] = f2b(v - b2f(hi));
            if (c.outm)  c.outm[arow(row, c.oS, c.oJ) * 1024 + col] = hi;
          }
        } else {
          v += b2f(c.addb[arow(row, 4, c.abJ) * 1024 + col]);
          int t = (row >> 3) * 4 + c.q, b = row & 7;
          c.hall[(size_t)t * 8192 + b * 1024 + col] = v;
          float sg = 1.f / (1.f + __expf(-v));
          c.out0[(size_t)(t - 1) * 8192 + b * 1024 + col] = v * v * sg;
          if (c.outb) c.outb[(size_t)row * 1024 + col] = f2b(v);
        }
      }
}

// ---- power iteration + misc helpers -----------------------------------------
__global__ void k_init(const float* __restrict__ u_in, const float* __restrict__ h0,
                       float* __restrict__ u_cur, float* __restrict__ v_acc,
                       float* __restrict__ u_acc, float* __restrict__ hall0)
{
  int i = blockIdx.x * 256 + threadIdx.x;
  if (i < 1024) { u_cur[i] = u_in[i]; v_acc[i] = 0.f; u_acc[i] = 0.f; }
  if (i < 8192) hall0[i] = h0[i];
}

// boundary seeds (launched AFTER pre-GEMM — lives over xb's old region)
__global__ void k_bnd0(const float* __restrict__ h0, float* __restrict__ bndS,
                       u16* __restrict__ bndSb, u16* __restrict__ bndSlo,
                       u16* __restrict__ bndb)
{
  int i = blockIdx.x * 256 + threadIdx.x;
  float h = h0[i];
  bndS[i] = h;
  u16 hi = f2b(h);
  bndSb[i] = hi;
  bndSlo[i] = f2b(h - b2f(hi));
  bndb[i] = hi;
}

__global__ void k_v(const float* __restrict__ W, const float* __restrict__ u_cur,
                    float* __restrict__ v_acc)
{
  int d = blockIdx.x * 256 + threadIdx.x;
  int e0 = blockIdx.y * 64;
  float a = 0.f;
  for (int e = e0; e < e0 + 64; ++e) a += W[(size_t)e * 1024 + d] * u_cur[e];
  atomicAdd(&v_acc[d], a);
}

__global__ void k_u(const float* __restrict__ W, const float* __restrict__ v_cur,
                    float* __restrict__ u_acc)
{
  int lg = threadIdx.x & 15, ei = threadIdx.x >> 4;
  int e = blockIdx.y * 16 + ei;
  int d0 = blockIdx.x * 512;
  float a = 0.f;
  for (int i = 0; i < 32; ++i) { int d = d0 + lg + 16 * i; a += W[(size_t)e * 1024 + d] * v_cur[d]; }
#pragma unroll
  for (int m = 1; m < 16; m <<= 1) a += __shfl_xor(a, m);
  if (lg == 0) atomicAdd(&u_acc[e], a);
}

__global__ void k_norm(const float* __restrict__ acc, float* __restrict__ outv,
                       float* __restrict__ z1)
{
  __shared__ float red[16];
  int t = threadIdx.x;
  float x = acc[t];
  float ss = x * x;
#pragma unroll
  for (int m = 1; m < 64; m <<= 1) ss += __shfl_xor(ss, m);
  if ((t & 63) == 0) red[t >> 6] = ss;
  __syncthreads();
  if (t < 64) {
    float s = (t < 16) ? red[t] : 0.f;
#pragma unroll
    for (int m = 1; m < 16; m <<= 1) s += __shfl_xor(s, m);
    if (t == 0) red[0] = s;
  }
  __syncthreads();
  float nrm = sqrtf(red[0]) + 1e-8f;
  outv[t] = x / nrm;
  z1[t] = 0.f;
}

__global__ void k_sigma(const float* __restrict__ acc, float* __restrict__ scale)
{
  __shared__ float red[16];
  int t = threadIdx.x;
  float x = acc[t];
  float ss = x * x;
#pragma unroll
  for (int m = 1; m < 64; m <<= 1) ss += __shfl_xor(ss, m);
  if ((t & 63) == 0) red[t >> 6] = ss;
  __syncthreads();
  if (t < 64) {
    float s = (t < 16) ? red[t] : 0.f;
#pragma unroll
    for (int m = 1; m < 16; m <<= 1) s += __shfl_xor(s, m);
    if (t == 0) {
      float sigma = s / (sqrtf(s) + 1e-8f);
      scale[0] = 0.95f / (sigma + 1e-8f);
    }
  }
}

__global__ void k_prep(const float* __restrict__ Wh, const float* __restrict__ Wx,
                       const float* __restrict__ scale, u16* __restrict__ wh_b,
                       u16* __restrict__ whT, u16* __restrict__ wxb)
{
  int i = blockIdx.x * 256 + threadIdx.x;
  float s = scale[0];
  int e = i >> 10, d = i & 1023;
  u16 hw = f2b(Wh[i] * s);
  wh_b[i] = hw;
  whT[(size_t)d * 1024 + e] = hw;
  wxb[i] = f2b(Wx[i]);
}

__global__ void k_cvt(const float* __restrict__ in, u16* __restrict__ out, int n)
{
  int i = (blockIdx.x * 256 + threadIdx.x) * 4;
  if (i >= n) return;
  float4 v = *(const float4*)(in + i);
  ushort4 o;
  o.x = f2b(v.x); o.y = f2b(v.y); o.z = f2b(v.z); o.w = f2b(v.w);
  *(ushort4*)(out + i) = o;
}

__global__ void k_gather(const float* __restrict__ lC, u16* __restrict__ lamH,
                         u16* __restrict__ lamL)
{
  int i = blockIdx.x * 256 + threadIdx.x;
  int r = i >> 8, e4 = (i & 255) * 4;
  int src = (r >> 3) * 128 + (r & 7);
  float4 v = *(const float4*)(lC + (size_t)src * 1024 + e4);
  ushort4 hi, lo;
  hi.x = f2b(v.x); lo.x = f2b(v.x - b2f(hi.x));
  hi.y = f2b(v.y); lo.y = f2b(v.y - b2f(hi.y));
  hi.z = f2b(v.z); lo.z = f2b(v.z - b2f(hi.z));
  hi.w = f2b(v.w); lo.w = f2b(v.w - b2f(hi.w));
  *(ushort4*)(lamH + (size_t)r * 1024 + e4) = hi;
  *(ushort4*)(lamL + (size_t)r * 1024 + e4) = lo;
}

static void setseg(ZCfg& z, int i, const u16* A, int S, int J, const u16* B) {
  switch (i) {
    case 0: z.A0 = A; z.S0 = S; z.J0 = J; z.B0 = B; break;
    case 1: z.A1 = A; z.S1 = S; z.J1 = J; z.B1 = B; break;
    case 2: z.A2 = A; z.S2 = S; z.J2 = J; z.B2 = B; break;
    case 3: z.A3 = A; z.S3 = S; z.J3 = J; z.B3 = B; break;
    default: z.A4 = A; z.S4 = S; z.J4 = J; z.B4 = B; break;
  }
}

extern "C" void kernel_launch(void* const* d_in, const int* in_sizes, int n_in,
                              void* d_out, int out_size, void* d_ws, size_t ws_size,
                              hipStream_t stream)
{
  (void)in_sizes; (void)n_in; (void)out_size; (void)ws_size;
  const float* x  = (const float*)d_in[0];
  const float* h0 = (const float*)d_in[1];
  const float* Wx = (const float*)d_in[2];
  const float* Wh = (const float*)d_in[3];
  const float* bv = (const float*)d_in[4];
  const float* uv = (const float*)d_in[5];

  float* out0 = (float*)d_out;
  float* hall = out0 + 16777216;

  const size_t M1 = 1048576;
  // ---- ws: everything phase 3 reads ----
  char* ws = (char*)d_ws;
  u16*   pre_b = (u16*)(ws);                  // 32 MiB [16384,1024] bf16
  u16*   wh_b  = (u16*)(ws + 32 * M1);        // 2 MiB
  u16*   bnd_b = (u16*)(ws + 34 * M1);        // 8 MiB [4096,1024]
  u16*   lb0   = (u16*)(ws + 42 * M1);        // 8 MiB phase-3 chain ping
  float* u_cur = (float*)(ws + 50 * M1);
  float* v_cur = u_cur + 1024;
  float* v_acc = u_cur + 2048;
  float* u_acc = u_cur + 3072;
  float* scale = u_cur + 4096;

  // ---- out0 region: preF fp32 (dead before phase 3 writes out0) ----
  float* preF = out0;                          // [16384,1024] fp32 = 64 MiB

  // ---- hall scratch (HBS = hall + 32 KiB; 64 MiB; dead before phase 3) ----
  char* HBS = (char*)hall + 32768;
  u16*   xb   = (u16*)(HBS);                   // 32 MiB (dead after pre-GEMM)
  float* lC   = (float*)(HBS);                 // 16 MiB (over xb)
  u16*   lCb  = (u16*)(HBS + 16 * M1);         // 8 MiB
  float* lamF = (float*)(HBS + 24 * M1);       // 1 MiB
  u16* lamH0  = (u16*)(HBS + 25 * M1);
  u16* lamH1  = (u16*)(HBS + 25 * M1 + 524288);
  u16* lamL0  = (u16*)(HBS + 26 * M1);
  u16* lamL1  = (u16*)(HBS + 26 * M1 + 524288);
  float* bndS = (float*)(HBS + 27 * M1);       // 1 MiB
  u16* bndSb  = (u16*)(HBS + 28 * M1);
  u16* bndSlo = (u16*)(HBS + 28 * M1 + 524288);
  u16* pcH0   = (u16*)(HBS + 29 * M1);
  u16* pcH1   = (u16*)(HBS + 29 * M1 + 524288);
  u16* pcL0   = (u16*)(HBS + 30 * M1);
  u16* pcL1   = (u16*)(HBS + 30 * M1 + 524288);
  // weights area: 16 x 2MiB slots at HBS+32MiB
  auto slot = [&](int k) { return (u16*)(HBS + 32 * M1 + (size_t)k * 2 * M1); };
  u16* whT  = slot(0);   // -> W192 after L2
  u16* wxb  = slot(1);   // -> W256 after pre-GEMM
  u16* W2   = slot(2);
  u16* W2T  = slot(3);
  u16* W3   = slot(4);
  u16* W4   = slot(5);
  u16* W4T  = slot(6);
  u16* W8   = slot(7);
  u16* W8T  = slot(8);   // -> W128 after L4
  u16* W12  = slot(9);
  u16* W16  = slot(10);
  u16* W16T = slot(11);  // -> W128T after L5
  u16* W32  = slot(12);
  u16* W32T = slot(13);
  u16* W64  = slot(14);
  u16* W64T = slot(15);
  u16* W128 = W8T, *W128T = W16T, *W192 = whT, *W256 = wxb;

  k_init<<<32, 256, 0, stream>>>(uv, h0, u_cur, v_acc, u_acc, hall);

  for (int it = 0; it < 3; ++it) {
    k_v<<<dim3(4, 16), 256, 0, stream>>>(Wh, u_cur, v_acc);
    k_norm<<<1, 1024, 0, stream>>>(v_acc, v_cur, u_acc);
    k_u<<<dim3(2, 64), 256, 0, stream>>>(Wh, v_cur, u_acc);
    if (it < 2) k_norm<<<1, 1024, 0, stream>>>(u_acc, u_cur, v_acc);
    else        k_sigma<<<1, 1024, 0, stream>>>(u_acc, scale);
  }
  k_prep<<<4096, 256, 0, stream>>>(Wh, Wx, scale, wh_b, whT, wxb);
  k_cvt<<<16384, 256, 0, stream>>>(x, xb, 16777216);

  // ---- pre = x @ Wx^T + b : fp32 preF + bf16 pre_b ----
  { GArgs a{}; ZCfg& z = a.z0;
    setseg(z, 0, xb, 0, 0, wxb);
    z.nseg = 1; z.addc = bv; z.outf = preF; z.outb = pre_b;
    gU<1><<<dim3(16, 256, 1), 256, 0, stream>>>(a); }

  auto sqz = [](ZCfg& z, const u16* A, const u16* B, u16* o, u16* oT) {
    z.A0 = A; z.S0 = 0; z.J0 = 0; z.B0 = B; z.nseg = 1; z.outb = o; z.outbT = oT;
  };
  // ---- Wh powers: 8 launches ----
  { GArgs a{}; sqz(a.z0, wh_b, whT, W2, W2T);
    gU<0><<<dim3(16, 16, 1), 256, 0, stream>>>(a); }
  { GArgs a{}; sqz(a.z0, W2, whT, W3, nullptr); sqz(a.z1, W2, W2T, W4, W4T);
    gU<0><<<dim3(16, 16, 2), 256, 0, stream>>>(a); }
  { GArgs a{}; sqz(a.z0, W4, W4T, W8, W8T);
    gU<0><<<dim3(16, 16, 1), 256, 0, stream>>>(a); }
  { GArgs a{}; sqz(a.z0, W8, W4T, W12, nullptr); sqz(a.z1, W8, W8T, W16, W16T);
    gU<0><<<dim3(16, 16, 2), 256, 0, stream>>>(a); }
  { GArgs a{}; sqz(a.z0, W16, W16T, W32, W32T);
    gU<0><<<dim3(16, 16, 1), 256, 0, stream>>>(a); }
  { GArgs a{}; sqz(a.z0, W32, W32T, W64, W64T);
    gU<0><<<dim3(16, 16, 1), 256, 0, stream>>>(a); }
  { GArgs a{}; sqz(a.z0, W64, W64T, W128, W128T);
    gU<0><<<dim3(16, 16, 1), 256, 0, stream>>>(a); }
  { GArgs a{}; sqz(a.z0, W128, W64T, W192, nullptr); sqz(a.z1, W128, W128T, W256, nullptr);
    gU<0><<<dim3(16, 16, 2), 256, 0, stream>>>(a); }

  // ---- phase 1: lC = W3*pre0 + W2*pre1 + W*pre2 + pre3  (one GEMM) ----
  { GArgs a{}; ZCfg& z = a.z0;
    setseg(z, 0, pre_b, 4, 0, W3);
    setseg(z, 1, pre_b, 4, 1, W2);
    setseg(z, 2, pre_b, 4, 2, wh_b);
    z.nseg = 3; z.mvalid = 4096;
    z.addf = preF; z.addS = 4; z.addJ = 3;
    z.outf = lC; z.outb = lCb;
    gU<2><<<dim3(16, 64, 1), 256, 0, stream>>>(a); }

  // ---- boundary seeds (after xb is dead) ----
  k_bnd0<<<32, 256, 0, stream>>>(h0, bndS, bndSb, bndSlo, bnd_b);

  // ---- phase 2a: Lambda chain (gather + 3 quad + 1 final) ----
  k_gather<<<256, 256, 0, stream>>>(lC, lamH0, lamL0);
  {
    const u16 *chH = lamH0, *chL = lamL0;
    int j0s[3] = {1, 5, 9};
    int pp = 1;
    for (int i = 0; i < 3; ++i) {
      u16* nxH = pp ? lamH1 : lamH0;
      u16* nxL = pp ? lamL1 : lamL0;
      GArgs a{}; ZCfg& z = a.z0;
      setseg(z, 0, chH, 0, 0, W16); setseg(z, 1, chL, 0, 0, W16);
      setseg(z, 2, lCb, 16, j0s[i],     W12);
      setseg(z, 3, lCb, 16, j0s[i] + 1, W8);
      setseg(z, 4, lCb, 16, j0s[i] + 2, W4);
      z.nseg = 5; z.mvalid = 256;
      z.addf = lC; z.addS = 16; z.addJ = j0s[i] + 3;
      z.outb = nxH; z.outlo = nxL;
      gU<2><<<dim3(16, 4, 1), 256, 0, stream>>>(a);
      chH = nxH; chL = nxL; pp ^= 1;
    }
    GArgs a{}; ZCfg& z = a.z0;
    setseg(z, 0, chH, 0, 0, W12); setseg(z, 1, chL, 0, 0, W12);
    setseg(z, 2, lCb, 16, 13, W8); setseg(z, 3, lCb, 16, 14, W4);
    z.nseg = 4; z.mvalid = 256;
    z.addf = lC; z.addS = 16; z.addJ = 15;
    z.outf = lamF; z.outb = lamH0; z.outlo = lamL0;
    gU<2><<<dim3(16, 4, 1), 256, 0, stream>>>(a);
  }

  // ---- phase 2b: superchunk chain, 8 z-quad launches (M=8) ----
  {
    const u16* w64s[4] = { W64, W128, W192, W256 };
    for (int sb2 = 0; sb2 < 32; sb2 += 4) {
      int zmax = (sb2 == 28) ? 3 : 4;
      GArgs a{};
      ZCfg* zs[4] = { &a.z0, &a.z1, &a.z2, &a.z3 };
      for (int zz = 1; zz <= zmax; ++zz) {
        ZCfg& z = *zs[zz - 1];
        setseg(z, 0, bndSb + (size_t)sb2 * 8192, -1, 0, w64s[zz - 1]);
        int ns = 1;
        for (int i = 0; i < zz - 1; ++i)
          setseg(z, ns++, lamH0 + (size_t)(sb2 + i) * 8192, -1, 0, w64s[zz - 2 - i]);
        z.nseg = ns; z.mvalid = 8;
        z.addf = lamF + (size_t)(sb2 + zz - 1) * 8192; z.addS = -1;
        z.outb = bndSb + (size_t)(sb2 + zz) * 8192;
        z.outlo = bndSlo + (size_t)(sb2 + zz) * 8192;
        z.outm = bnd_b + (size_t)16 * (sb2 + zz) * 8192; z.oS = 0;
      }
      gU<2><<<dim3(16, 1, zmax), 256, 0, stream>>>(a);
    }
  }

  // ---- phase 2c: intra-super chunk boundaries, 4 z-quad launches ----
  {
    const u16* w4s[4] = { W4, W8, W12, W16 };
    const u16* cinH[4] = { bndSb, pcH0, pcH1, pcH0 };
    const u16* cinL[4] = { bndSlo, pcL0, pcL1, pcL0 };
    u16* coutH[4] = { pcH0, pcH1, pcH0, nullptr };
    u16* coutL[4] = { pcL0, pcL1, pcL0, nullptr };
    for (int t4 = 0; t4 < 4; ++t4) {
      int jb = 4 * t4;
      int zmax = (t4 == 3) ? 3 : 4;
      GArgs a{};
      ZCfg* zs[4] = { &a.z0, &a.z1, &a.z2, &a.z3 };
      for (int zz = 1; zz <= zmax; ++zz) {
        ZCfg& z = *zs[zz - 1];
        setseg(z, 0, cinH[t4], 0, 0, w4s[zz - 1]);
        setseg(z, 1, cinL[t4], 0, 0, w4s[zz - 1]);
        int ns = 2;
        for (int i = 0; i < zz - 1; ++i)
          setseg(z, ns++, lCb, 16, jb + i, w4s[zz - 2 - i]);
        z.nseg = ns; z.mvalid = 256;
        z.addf = lC; z.addS = 16; z.addJ = jb + zz - 1;
        z.outm = bnd_b; z.oS = 16; z.oJ = jb + zz;
        if (zz == 4) { z.outb = coutH[t4]; z.outlo = coutL[t4]; }
      }
      gU<2><<<dim3(16, 4, zmax), 256, 0, stream>>>(a);
    }
  }

  // ---- phase 3: 4 sequential K=1024 GEMMs, fused h_all + h^2*silu ----
  {
    const u16* ins[4]  = { bnd_b, lb0, bnd_b, lb0 };  // q2 overwrites bnd_b (dead)
    u16*       outs[4] = { lb0, bnd_b, lb0, nullptr };
    for (int q = 1; q <= 4; ++q) {
      GArgs a{}; ZCfg& z = a.z0;
      setseg(z, 0, ins[q - 1], 0, 0, wh_b);
      z.nseg = 1; z.q = q;
      z.addb = pre_b; z.abJ = q - 1;
      z.hall = hall; z.out0 = out0;
      z.outb = outs[q - 1];
      gU<3><<<dim3(16, 64, 1), 256, 0, stream>>>(a);
    }
  }
}